// Round 10
// baseline (174.993 us; speedup 1.0000x reference)
//
#include <hip/hip_runtime.h>

typedef unsigned short u16;
typedef __bf16 b16x8_t __attribute__((ext_vector_type(8)));
typedef unsigned short u16x8 __attribute__((ext_vector_type(8)));
typedef float f32x4 __attribute__((ext_vector_type(4)));

__device__ __forceinline__ u16 f2bf(float f) {
  union { float f; unsigned u; } x; x.f = f;
  unsigned r = x.u + 0x7fffu + ((x.u >> 16) & 1u);
  return (u16)(r >> 16);
}

__device__ __forceinline__ f32x4 mfma16(u16x8 a, u16x8 b, f32x4 c) {
  return __builtin_amdgcn_mfma_f32_16x16x32_bf16(
      __builtin_bit_cast(b16x8_t, a), __builtin_bit_cast(b16x8_t, b), c, 0, 0, 0);
}

__device__ __forceinline__ void gld_lds16(const void* g, void* l) {
  __builtin_amdgcn_global_load_lds(
      (const __attribute__((address_space(1))) void*)g,
      (__attribute__((address_space(3))) void*)l, 16, 0, 0);
}

__device__ __forceinline__ void store_out(float* p, float v) { *p = v; }
__device__ __forceinline__ void store_out(u16* p, float v) { *p = f2bf(v); }

// ---------------- elementwise f32 -> bf16 ----------------
__global__ void convert_bf16(const float* __restrict__ src, u16* __restrict__ dst, int n4) {
  int i = blockIdx.x * blockDim.x + threadIdx.x;
  if (i < n4) {
    float4 f = ((const float4*)src)[i];
    u16 a0 = f2bf(f.x), a1 = f2bf(f.y), a2 = f2bf(f.z), a3 = f2bf(f.w);
    unsigned lo = (unsigned)a0 | ((unsigned)a1 << 16);
    unsigned hi = (unsigned)a2 | ((unsigned)a3 << 16);
    ((uint2*)dst)[i] = make_uint2(lo, hi);
  }
}

// ---------------- f32 [R][C] -> bf16 transposed [C][R] ----------------
__global__ void transpose_f32_bf16(const float* __restrict__ src, u16* __restrict__ dst,
                                   int R, int Cn) {
  __shared__ float t[32][33];
  int c0 = blockIdx.x * 32, r0 = blockIdx.y * 32;
  int tx = threadIdx.x, ty = threadIdx.y;  // (32,8)
  for (int j = 0; j < 32; j += 8)
    t[ty + j][tx] = src[(size_t)(r0 + ty + j) * Cn + c0 + tx];
  __syncthreads();
  for (int j = 0; j < 32; j += 8)
    dst[(size_t)(c0 + ty + j) * R + r0 + tx] = f2bf(t[tx][ty + j]);
}

// ---------------- bf16 GEMM v7: C[M][N] = A[M][K] * Bt[N][K]^T ----------------
// (unchanged from R9 -- best GEMM structure measured: GEMM1 75us, GEMM2 ~13us)
template <typename OutT, int BN, int EPI>
__global__ __launch_bounds__(256, 2) void gemm_v7(const u16* __restrict__ A,
                                                  const u16* __restrict__ Bt,
                                                  OutT* __restrict__ C,
                                                  u16* __restrict__ Vt,
                                                  int M, int N, int K) {
  constexpr int NB = BN / 64;
  constexpr int NJ = BN / 32;
  constexpr int NL = 2 + NB;
  __shared__ __align__(16) u16 sA[3][4096];
  __shared__ __align__(16) u16 sB[3][BN * 32];
  const int tid = threadIdx.x, lane = tid & 63, wid = tid >> 6;
  const int hi = lane >> 4, ln = lane & 15;
  const int wm = (wid >> 1) * 64, wn = (wid & 1) * (BN / 2);

  const int gdx = gridDim.x;
  const int nwg = gdx * gridDim.y;
  int wg = blockIdx.y * gdx + blockIdx.x;
  wg = (wg & 7) * (nwg >> 3) + (wg >> 3);
  const int m0 = (wg / gdx) * 128;
  const int n0 = (wg % gdx) * BN;

  const int sr = tid >> 2;
  const int scsw = ((tid & 3) ^ ((tid >> 3) & 3)) * 8;
  const u16* srcA = A + (size_t)(m0 + sr) * K + scsw;
  const u16* srcB = Bt + (size_t)(n0 + sr) * K + scsw;
  const size_t K64 = (size_t)64 * K;

  auto stage = [&](int buf, int t) {
    const int k0 = t * 32;
    gld_lds16(srcA + k0, &sA[buf][tid * 8]);
    gld_lds16(srcA + K64 + k0, &sA[buf][2048 + tid * 8]);
    gld_lds16(srcB + k0, &sB[buf][tid * 8]);
    gld_lds16(srcB + K64 + k0, &sB[buf][2048 + tid * 8]);
    if (NB > 2) gld_lds16(srcB + 2 * K64 + k0, &sB[buf][4096 + tid * 8]);
  };

  const int csw = (hi ^ ((ln >> 1) & 3)) * 8;
  int offA[4], offB[NJ];
#pragma unroll
  for (int i = 0; i < 4; ++i) offA[i] = (wm + i * 16 + ln) * 32 + csw;
#pragma unroll
  for (int j = 0; j < NJ; ++j) offB[j] = (wn + j * 16 + ln) * 32 + csw;

  f32x4 acc[4][NJ] = {};
  const int NT = K >> 5;

  stage(0, 0); stage(1, 1);
  if constexpr (NL == 5) asm volatile("s_waitcnt vmcnt(5)" ::: "memory");
  else                   asm volatile("s_waitcnt vmcnt(4)" ::: "memory");
  __builtin_amdgcn_s_barrier();

  int cb = 0, sb = 2;
  for (int kt = 0; kt < NT; ++kt) {
    u16x8 af[4], bf[NJ];
#pragma unroll
    for (int i = 0; i < 4; ++i) af[i] = *(const u16x8*)(&sA[cb][offA[i]]);
#pragma unroll
    for (int j = 0; j < NJ; ++j) bf[j] = *(const u16x8*)(&sB[cb][offB[j]]);
    if (kt + 2 < NT) {
      stage(sb, kt + 2);
      sb = (sb == 2) ? 0 : sb + 1;
      if constexpr (NL == 5) asm volatile("s_waitcnt vmcnt(5)" ::: "memory");
      else                   asm volatile("s_waitcnt vmcnt(4)" ::: "memory");
    } else {
      asm volatile("s_waitcnt vmcnt(0)" ::: "memory");
    }
    __builtin_amdgcn_s_barrier();
    asm volatile("s_waitcnt lgkmcnt(0)" ::: "memory");
    __builtin_amdgcn_sched_barrier(0);
    __builtin_amdgcn_s_setprio(1);
#pragma unroll
    for (int i = 0; i < 4; ++i)
#pragma unroll
      for (int j = 0; j < NJ; ++j)
        acc[i][j] = mfma16(af[i], bf[j], acc[i][j]);
    __builtin_amdgcn_s_setprio(0);
    __builtin_amdgcn_sched_barrier(0);
    __builtin_amdgcn_s_barrier();
    cb = (cb == 2) ? 0 : cb + 1;
  }

#pragma unroll
  for (int i = 0; i < 4; ++i) {
    int rr = m0 + wm + i * 16 + hi * 4;
#pragma unroll
    for (int j = 0; j < NJ; ++j) {
      int colw = wn + j * 16 + ln;
      if (EPI == 1 && colw >= 128) {
        int h = n0 / 192, kk = colw - 128;
        int b = rr >> 10, n = rr & 1023;
        ushort4 pk;
        pk.x = f2bf(acc[i][j][0]); pk.y = f2bf(acc[i][j][1]);
        pk.z = f2bf(acc[i][j][2]); pk.w = f2bf(acc[i][j][3]);
        *(ushort4*)(Vt + ((size_t)(b * 16 + h) * 64 + kk) * 1024 + n) = pk;
      } else {
        float sc = (EPI == 1 && colw < 64) ? 0.125f : 1.f;
        int col = n0 + colw;
#pragma unroll
        for (int r = 0; r < 4; ++r)
          store_out(&C[(size_t)(rr + r) * N + col], acc[i][j][r] * sc);
      }
    }
  }
}

// ---------------- causal flash attention v3 ----------------
// 4 waves x 32 q-rows (QBLK=32/wave): per KV-tile 16+16 MFMA per wave; K/V
// fragments loaded ONCE per wave and reused across both 16-row subtiles --
// halves per-tile stage/barrier/fragment overhead vs v2 (8 waves x 16 rows).
// grid (z=4, h=16, b=8) x 256 thr; block does q-tiles z and 7-z (balanced 18
// KV-iters). LDS 50KB -> 3 blocks/CU. + T5 setprio on MFMA clusters;
// + T13 defer-max (THR=8): skip O-rescale when __all(tm <= m+8).
__global__ __launch_bounds__(256, 3) void attn_fwd3(const u16* __restrict__ QKV,
                                                    const u16* __restrict__ Vt,
                                                    u16* __restrict__ O) {
  __shared__ __align__(16) u16 sK[2][4096];
  __shared__ __align__(16) u16 sVt[2][4096];
  __shared__ __align__(16) u16 sP[4][32 * 72];
  const int tid = threadIdx.x, lane = tid & 63, wid = tid >> 6;
  const int z = blockIdx.x, h = blockIdx.y, bb = blockIdx.z;
  const size_t rowbase = (size_t)bb * 1024;
  const size_t vbase = ((size_t)bb * 16 + h) * 64;
  const int colQ = h * 192, colK = colQ + 64;
  const int hi = lane >> 4, ln = lane & 15;
  const int slr = lane >> 3;
  const int sle = ((lane & 7) ^ slr) * 8;
  u16* sPw = sP[wid];

  auto stageKV = [&](int buf, int nt) {
    const int n0g = nt * 64;
#pragma unroll
    for (int cc = 0; cc < 2; ++cc) {
      int c = wid * 2 + cc;
      gld_lds16(QKV + (rowbase + n0g + c * 8 + slr) * 3072 + colK + sle,
                &sK[buf][c * 512]);
      gld_lds16(Vt + (vbase + c * 8 + slr) * 1024 + n0g + sle,
                &sVt[buf][c * 512]);
    }
  };

  for (int half = 0; half < 2; ++half) {
    const int mt = half ? (7 - z) : z;
    const int qrow0 = mt * 128 + wid * 32;
    const int ntiles = 2 * mt + 2;

    u16x8 qf[2][2];
#pragma unroll
    for (int i = 0; i < 2; ++i)
#pragma unroll
      for (int kb = 0; kb < 2; ++kb)
        qf[i][kb] = *(const u16x8*)(QKV + (rowbase + qrow0 + i * 16 + ln) * 3072 +
                                    colQ + kb * 32 + hi * 8);

    f32x4 o[2][4] = {};
    float mrow[2][4], lrow[2][4];
#pragma unroll
    for (int i = 0; i < 2; ++i)
#pragma unroll
      for (int r = 0; r < 4; ++r) { mrow[i][r] = -1e30f; lrow[i][r] = 0.f; }

    stageKV(0, 0);
    for (int nt = 0; nt < ntiles; ++nt) {
      __syncthreads();
      if (nt + 1 < ntiles) stageKV((nt + 1) & 1, nt + 1);
      const int buf = nt & 1;
      const int n0g = nt * 64;
      if (n0g <= qrow0 + 31) {               // wave-uniform skip of masked tiles
        // S = Q K^T : kf loaded once, reused for both i-subtiles
        f32x4 s[2][4] = {};
        __builtin_amdgcn_s_setprio(1);
#pragma unroll
        for (int kb = 0; kb < 2; ++kb) {
          u16x8 kf[4];
#pragma unroll
          for (int j = 0; j < 4; ++j) {
            int row = j * 16 + ln;
            int cbk = (kb * 64 + hi * 16) ^ ((row & 7) << 4);
            kf[j] = *(const u16x8*)(&sK[buf][(row * 128 + cbk) >> 1]);
          }
#pragma unroll
          for (int i = 0; i < 2; ++i)
#pragma unroll
            for (int j = 0; j < 4; ++j)
              s[i][j] = mfma16(qf[i][kb], kf[j], s[i][j]);
        }
        __builtin_amdgcn_s_setprio(0);
        // causal mask (diagonal-touching tiles only)
        if (n0g + 63 > qrow0) {
#pragma unroll
          for (int i = 0; i < 2; ++i)
#pragma unroll
            for (int j = 0; j < 4; ++j) {
              int col = n0g + j * 16 + ln;
              int rq = qrow0 + i * 16 + hi * 4;
#pragma unroll
              for (int r = 0; r < 4; ++r)
                if (col > rq + r) s[i][j][r] = -3e38f;
            }
        }
        // online softmax with defer-max (THR=8)
#pragma unroll
        for (int i = 0; i < 2; ++i) {
#pragma unroll
          for (int r = 0; r < 4; ++r) {
            float tm = fmaxf(fmaxf(s[i][0][r], s[i][1][r]),
                             fmaxf(s[i][2][r], s[i][3][r]));
#pragma unroll
            for (int d = 1; d < 16; d <<= 1) tm = fmaxf(tm, __shfl_xor(tm, d, 64));
            if (!__all(tm <= mrow[i][r] + 8.f)) {
              float mnew = fmaxf(mrow[i][r], tm);
              float corr = __expf(mrow[i][r] - mnew);
              mrow[i][r] = mnew;
              lrow[i][r] *= corr;
#pragma unroll
              for (int dt = 0; dt < 4; ++dt) o[i][dt][r] *= corr;
            }
            float rs = 0.f;
#pragma unroll
            for (int j = 0; j < 4; ++j) {
              float p = __expf(s[i][j][r] - mrow[i][r]);
              s[i][j][r] = p;
              rs += p;
            }
#pragma unroll
            for (int d = 1; d < 16; d <<= 1) rs += __shfl_xor(rs, d, 64);
            lrow[i][r] += rs;
          }
          // P -> per-wave LDS
#pragma unroll
          for (int j = 0; j < 4; ++j)
#pragma unroll
            for (int r = 0; r < 4; ++r)
              sPw[(i * 16 + hi * 4 + r) * 72 + j * 16 + ln] = f2bf(s[i][j][r]);
        }
        // O += P V : vfr loaded once per (dt,kb2), reused for both i
        u16x8 pf[2][2];
#pragma unroll
        for (int i = 0; i < 2; ++i)
#pragma unroll
          for (int kb2 = 0; kb2 < 2; ++kb2)
            pf[i][kb2] = *(const u16x8*)(&sPw[(i * 16 + ln) * 72 + kb2 * 32 + hi * 8]);
        __builtin_amdgcn_s_setprio(1);
#pragma unroll
        for (int dt = 0; dt < 4; ++dt)
#pragma unroll
          for (int kb2 = 0; kb2 < 2; ++kb2) {
            int row = dt * 16 + ln;
            int cbk = (kb2 * 64 + hi * 16) ^ ((row & 7) << 4);
            u16x8 vfr = *(const u16x8*)(&sVt[buf][(row * 128 + cbk) >> 1]);
#pragma unroll
            for (int i = 0; i < 2; ++i)
              o[i][dt] = mfma16(pf[i][kb2], vfr, o[i][dt]);
          }
        __builtin_amdgcn_s_setprio(0);
      }
    }
    // write O
#pragma unroll
    for (int i = 0; i < 2; ++i)
#pragma unroll
      for (int r = 0; r < 4; ++r) {
        float inv = 1.f / lrow[i][r];
#pragma unroll
        for (int dt = 0; dt < 4; ++dt)
          O[(rowbase + qrow0 + i * 16 + hi * 4 + r) * 1024 + h * 64 + dt * 16 + ln] =
              f2bf(o[i][dt][r] * inv);
      }
  }
}

extern "C" void kernel_launch(void* const* d_in, const int* in_sizes, int n_in,
                              void* d_out, int out_size, void* d_ws, size_t ws_size,
                              hipStream_t stream) {
  const float* x = (const float*)d_in[0];
  const float* Pi = (const float*)d_in[1];
  const float* Po = (const float*)d_in[2];
  float* y = (float*)d_out;
  char* ws = (char*)d_ws;

  u16* qkv  = (u16*)(ws);                     // 0        .. 50331648
  u16* piT  = (u16*)(ws + 50331648);          // 50331648 .. 56623104
  u16* poT  = (u16*)(ws + 56623104);          // 56623104 .. 58720256
  u16* xbf  = (u16*)(ws + 58720256);          // 58720256 .. 75497472 (dead after GEMM1)
  u16* vt   = (u16*)(ws + 75497472);          // 75497472 .. 92274688
  u16* obuf = (u16*)(ws + 58720256);          // reuses xbf slot

  convert_bf16<<<8192, 256, 0, stream>>>(x, xbf, 8388608 / 4);
  dim3 tb(32, 8);
  transpose_f32_bf16<<<dim3(96, 32), tb, 0, stream>>>(Pi, piT, 1024, 3072);
  transpose_f32_bf16<<<dim3(32, 32), tb, 0, stream>>>(Po, poT, 1024, 1024);

  gemm_v7<u16, 192, 1><<<dim3(16, 64), 256, 0, stream>>>(xbf, piT, qkv, vt,
                                                         8192, 3072, 1024);
  attn_fwd3<<<dim3(4, 16, 8), 256, 0, stream>>>(qkv, vt, obuf);
  gemm_v7<float, 128, 0><<<dim3(8, 64), 256, 0, stream>>>(obuf, poT, y, nullptr,
                                                          8192, 1024, 1024);
}

// Round 11
// 153.338 us; speedup vs baseline: 1.1412x; 1.1412x over previous
//
#include <hip/hip_runtime.h>

typedef unsigned short u16;
typedef __bf16 b16x8_t __attribute__((ext_vector_type(8)));
typedef unsigned short u16x8 __attribute__((ext_vector_type(8)));
typedef float f32x4 __attribute__((ext_vector_type(4)));

__device__ __forceinline__ u16 f2bf(float f) {
  union { float f; unsigned u; } x; x.f = f;
  unsigned r = x.u + 0x7fffu + ((x.u >> 16) & 1u);
  return (u16)(r >> 16);
}

__device__ __forceinline__ f32x4 mfma16(u16x8 a, u16x8 b, f32x4 c) {
  return __builtin_amdgcn_mfma_f32_16x16x32_bf16(
      __builtin_bit_cast(b16x8_t, a), __builtin_bit_cast(b16x8_t, b), c, 0, 0, 0);
}

__device__ __forceinline__ void gld_lds16(const void* g, void* l) {
  __builtin_amdgcn_global_load_lds(
      (const __attribute__((address_space(1))) void*)g,
      (__attribute__((address_space(3))) void*)l, 16, 0, 0);
}

__device__ __forceinline__ void store_out(float* p, float v) { *p = v; }
__device__ __forceinline__ void store_out(u16* p, float v) { *p = f2bf(v); }

// ---------------- elementwise f32 -> bf16 ----------------
__global__ void convert_bf16(const float* __restrict__ src, u16* __restrict__ dst, int n4) {
  int i = blockIdx.x * blockDim.x + threadIdx.x;
  if (i < n4) {
    float4 f = ((const float4*)src)[i];
    u16 a0 = f2bf(f.x), a1 = f2bf(f.y), a2 = f2bf(f.z), a3 = f2bf(f.w);
    unsigned lo = (unsigned)a0 | ((unsigned)a1 << 16);
    unsigned hi = (unsigned)a2 | ((unsigned)a3 << 16);
    ((uint2*)dst)[i] = make_uint2(lo, hi);
  }
}

// ---------------- f32 [R][C] -> bf16 transposed [C][R] ----------------
__global__ void transpose_f32_bf16(const float* __restrict__ src, u16* __restrict__ dst,
                                   int R, int Cn) {
  __shared__ float t[32][33];
  int c0 = blockIdx.x * 32, r0 = blockIdx.y * 32;
  int tx = threadIdx.x, ty = threadIdx.y;  // (32,8)
  for (int j = 0; j < 32; j += 8)
    t[ty + j][tx] = src[(size_t)(r0 + ty + j) * Cn + c0 + tx];
  __syncthreads();
  for (int j = 0; j < 32; j += 8)
    dst[(size_t)(c0 + ty + j) * R + r0 + tx] = f2bf(t[tx][ty + j]);
}

// ---------------- bf16 GEMM v7: C[M][N] = A[M][K] * Bt[N][K]^T ----------------
// (unchanged from R9 -- best GEMM structure measured: GEMM1 75us, GEMM2 ~13us)
template <typename OutT, int BN, int EPI>
__global__ __launch_bounds__(256, 2) void gemm_v7(const u16* __restrict__ A,
                                                  const u16* __restrict__ Bt,
                                                  OutT* __restrict__ C,
                                                  u16* __restrict__ Vt,
                                                  int M, int N, int K) {
  constexpr int NB = BN / 64;
  constexpr int NJ = BN / 32;
  constexpr int NL = 2 + NB;
  __shared__ __align__(16) u16 sA[3][4096];
  __shared__ __align__(16) u16 sB[3][BN * 32];
  const int tid = threadIdx.x, lane = tid & 63, wid = tid >> 6;
  const int hi = lane >> 4, ln = lane & 15;
  const int wm = (wid >> 1) * 64, wn = (wid & 1) * (BN / 2);

  const int gdx = gridDim.x;
  const int nwg = gdx * gridDim.y;
  int wg = blockIdx.y * gdx + blockIdx.x;
  wg = (wg & 7) * (nwg >> 3) + (wg >> 3);
  const int m0 = (wg / gdx) * 128;
  const int n0 = (wg % gdx) * BN;

  const int sr = tid >> 2;
  const int scsw = ((tid & 3) ^ ((tid >> 3) & 3)) * 8;
  const u16* srcA = A + (size_t)(m0 + sr) * K + scsw;
  const u16* srcB = Bt + (size_t)(n0 + sr) * K + scsw;
  const size_t K64 = (size_t)64 * K;

  auto stage = [&](int buf, int t) {
    const int k0 = t * 32;
    gld_lds16(srcA + k0, &sA[buf][tid * 8]);
    gld_lds16(srcA + K64 + k0, &sA[buf][2048 + tid * 8]);
    gld_lds16(srcB + k0, &sB[buf][tid * 8]);
    gld_lds16(srcB + K64 + k0, &sB[buf][2048 + tid * 8]);
    if (NB > 2) gld_lds16(srcB + 2 * K64 + k0, &sB[buf][4096 + tid * 8]);
  };

  const int csw = (hi ^ ((ln >> 1) & 3)) * 8;
  int offA[4], offB[NJ];
#pragma unroll
  for (int i = 0; i < 4; ++i) offA[i] = (wm + i * 16 + ln) * 32 + csw;
#pragma unroll
  for (int j = 0; j < NJ; ++j) offB[j] = (wn + j * 16 + ln) * 32 + csw;

  f32x4 acc[4][NJ] = {};
  const int NT = K >> 5;

  stage(0, 0); stage(1, 1);
  if constexpr (NL == 5) asm volatile("s_waitcnt vmcnt(5)" ::: "memory");
  else                   asm volatile("s_waitcnt vmcnt(4)" ::: "memory");
  __builtin_amdgcn_s_barrier();

  int cb = 0, sb = 2;
  for (int kt = 0; kt < NT; ++kt) {
    u16x8 af[4], bf[NJ];
#pragma unroll
    for (int i = 0; i < 4; ++i) af[i] = *(const u16x8*)(&sA[cb][offA[i]]);
#pragma unroll
    for (int j = 0; j < NJ; ++j) bf[j] = *(const u16x8*)(&sB[cb][offB[j]]);
    if (kt + 2 < NT) {
      stage(sb, kt + 2);
      sb = (sb == 2) ? 0 : sb + 1;
      if constexpr (NL == 5) asm volatile("s_waitcnt vmcnt(5)" ::: "memory");
      else                   asm volatile("s_waitcnt vmcnt(4)" ::: "memory");
    } else {
      asm volatile("s_waitcnt vmcnt(0)" ::: "memory");
    }
    __builtin_amdgcn_s_barrier();
    asm volatile("s_waitcnt lgkmcnt(0)" ::: "memory");
    __builtin_amdgcn_sched_barrier(0);
    __builtin_amdgcn_s_setprio(1);
#pragma unroll
    for (int i = 0; i < 4; ++i)
#pragma unroll
      for (int j = 0; j < NJ; ++j)
        acc[i][j] = mfma16(af[i], bf[j], acc[i][j]);
    __builtin_amdgcn_s_setprio(0);
    __builtin_amdgcn_sched_barrier(0);
    __builtin_amdgcn_s_barrier();
    cb = (cb == 2) ? 0 : cb + 1;
  }

#pragma unroll
  for (int i = 0; i < 4; ++i) {
    int rr = m0 + wm + i * 16 + hi * 4;
#pragma unroll
    for (int j = 0; j < NJ; ++j) {
      int colw = wn + j * 16 + ln;
      if (EPI == 1 && colw >= 128) {
        int h = n0 / 192, kk = colw - 128;
        int b = rr >> 10, n = rr & 1023;
        ushort4 pk;
        pk.x = f2bf(acc[i][j][0]); pk.y = f2bf(acc[i][j][1]);
        pk.z = f2bf(acc[i][j][2]); pk.w = f2bf(acc[i][j][3]);
        *(ushort4*)(Vt + ((size_t)(b * 16 + h) * 64 + kk) * 1024 + n) = pk;
      } else {
        float sc = (EPI == 1 && colw < 64) ? 0.125f : 1.f;
        int col = n0 + colw;
#pragma unroll
        for (int r = 0; r < 4; ++r)
          store_out(&C[(size_t)(rr + r) * N + col], acc[i][j][r] * sc);
      }
    }
  }
}

// ---------------- causal flash attention v4 ----------------
// = R9's verified 8-wave v2 structure (512 thr, 16 q-rows/wave, latency-bound
// so wave count is king -- v3's 4-wave variant regressed 45%) + three grafts:
//  (a) row-sum via matrix pipe: lacc = mfma(P, ones) replaces the 4-step
//      shfl-sum chain (moves work VALU->MFMA, shortens serial chain),
//  (b) T13 defer-max THR=8: skip rescale unless a row max grew >8,
//  (c) T5 setprio around QK/PV MFMA clusters.
__global__ __launch_bounds__(512, 4) void attn_fwd4(const u16* __restrict__ QKV,
                                                    const u16* __restrict__ Vt,
                                                    u16* __restrict__ O) {
  __shared__ __align__(16) u16 sK[2][4096];
  __shared__ __align__(16) u16 sVt[2][4096];
  __shared__ __align__(16) u16 sP[8][16 * 72];
  const int tid = threadIdx.x, lane = tid & 63, wid = tid >> 6;
  const int z = blockIdx.x, h = blockIdx.y, bb = blockIdx.z;
  const size_t rowbase = (size_t)bb * 1024;
  const size_t vbase = ((size_t)bb * 16 + h) * 64;
  const int colQ = h * 192, colK = colQ + 64;
  const int hi = lane >> 4, ln = lane & 15;
  const int slr = lane >> 3;
  const int sle = ((lane & 7) ^ slr) * 8;
  u16* sPw = sP[wid];
  const u16x8 onesf = {0x3F80, 0x3F80, 0x3F80, 0x3F80, 0x3F80, 0x3F80, 0x3F80, 0x3F80};

  auto stageKV = [&](int buf, int nt) {
    const int n0g = nt * 64;
    gld_lds16(QKV + (rowbase + n0g + 8 * wid + slr) * 3072 + colK + sle,
              &sK[buf][wid * 512]);
    gld_lds16(Vt + (vbase + 8 * wid + slr) * 1024 + n0g + sle,
              &sVt[buf][wid * 512]);
  };

  for (int half = 0; half < 2; ++half) {
    const int mt = half ? (7 - z) : z;
    const int qrow0 = mt * 128 + wid * 16;
    const int ntiles = 2 * mt + 2;

    u16x8 qf[2];
#pragma unroll
    for (int kb = 0; kb < 2; ++kb)
      qf[kb] = *(const u16x8*)(QKV + (rowbase + qrow0 + ln) * 3072 + colQ + kb * 32 + hi * 8);

    f32x4 o[4] = {};
    f32x4 lacc = {0.f, 0.f, 0.f, 0.f};
    float mrow[4];
#pragma unroll
    for (int r = 0; r < 4; ++r) mrow[r] = -1e30f;

    stageKV(0, 0);
    for (int nt = 0; nt < ntiles; ++nt) {
      __syncthreads();
      if (nt + 1 < ntiles) stageKV((nt + 1) & 1, nt + 1);
      const int buf = nt & 1;
      const int n0g = nt * 64;
      if (n0g <= qrow0 + 15) {
        f32x4 s[4] = {};
        __builtin_amdgcn_s_setprio(1);
#pragma unroll
        for (int kb = 0; kb < 2; ++kb)
#pragma unroll
          for (int j = 0; j < 4; ++j) {
            int row = j * 16 + ln;
            int cb = (kb * 64 + hi * 16) ^ ((row & 7) << 4);
            u16x8 kfr = *(const u16x8*)(&sK[buf][(row * 128 + cb) >> 1]);
            s[j] = mfma16(qf[kb], kfr, s[j]);
          }
        __builtin_amdgcn_s_setprio(0);
        if (n0g + 63 > qrow0) {
#pragma unroll
          for (int j = 0; j < 4; ++j) {
            int col = n0g + j * 16 + ln;
#pragma unroll
            for (int r = 0; r < 4; ++r)
              if (col > qrow0 + hi * 4 + r) s[j][r] = -3e38f;
          }
        }
        // row max (shfl) + defer-max rescale; row SUM moved to matrix pipe
        float tmv[4];
#pragma unroll
        for (int r = 0; r < 4; ++r) {
          float tm = fmaxf(fmaxf(s[0][r], s[1][r]), fmaxf(s[2][r], s[3][r]));
#pragma unroll
          for (int d = 1; d < 16; d <<= 1) tm = fmaxf(tm, __shfl_xor(tm, d, 64));
          tmv[r] = tm;
        }
        bool need = (tmv[0] > mrow[0] + 8.f) | (tmv[1] > mrow[1] + 8.f) |
                    (tmv[2] > mrow[2] + 8.f) | (tmv[3] > mrow[3] + 8.f);
        if (__any(need)) {
#pragma unroll
          for (int r = 0; r < 4; ++r) {
            float mnew = fmaxf(mrow[r], tmv[r]);
            float corr = __expf(mrow[r] - mnew);
            mrow[r] = mnew;
            lacc[r] *= corr;
#pragma unroll
            for (int dt = 0; dt < 4; ++dt) o[dt][r] *= corr;
          }
        }
#pragma unroll
        for (int j = 0; j < 4; ++j)
#pragma unroll
          for (int r = 0; r < 4; ++r)
            sPw[(hi * 4 + r) * 72 + j * 16 + ln] = f2bf(__expf(s[j][r] - mrow[r]));
        // O += P V ; lacc += P * ones (row-sum on the matrix pipe)
        u16x8 pf[2];
#pragma unroll
        for (int kb2 = 0; kb2 < 2; ++kb2)
          pf[kb2] = *(const u16x8*)(&sPw[ln * 72 + kb2 * 32 + hi * 8]);
        __builtin_amdgcn_s_setprio(1);
        lacc = mfma16(pf[0], onesf, lacc);
        lacc = mfma16(pf[1], onesf, lacc);
#pragma unroll
        for (int dt = 0; dt < 4; ++dt)
#pragma unroll
          for (int kb2 = 0; kb2 < 2; ++kb2) {
            int row = dt * 16 + ln;
            int cb = (kb2 * 64 + hi * 16) ^ ((row & 7) << 4);
            u16x8 vfr = *(const u16x8*)(&sVt[buf][(row * 128 + cb) >> 1]);
            o[dt] = mfma16(pf[kb2], vfr, o[dt]);
          }
        __builtin_amdgcn_s_setprio(0);
      }
    }
#pragma unroll
    for (int r = 0; r < 4; ++r) {
      float inv = 1.f / lacc[r];
#pragma unroll
      for (int dt = 0; dt < 4; ++dt)
        O[(rowbase + qrow0 + hi * 4 + r) * 1024 + h * 64 + dt * 16 + ln] =
            f2bf(o[dt][r] * inv);
    }
  }
}

extern "C" void kernel_launch(void* const* d_in, const int* in_sizes, int n_in,
                              void* d_out, int out_size, void* d_ws, size_t ws_size,
                              hipStream_t stream) {
  const float* x = (const float*)d_in[0];
  const float* Pi = (const float*)d_in[1];
  const float* Po = (const float*)d_in[2];
  float* y = (float*)d_out;
  char* ws = (char*)d_ws;

  u16* qkv  = (u16*)(ws);                     // 0        .. 50331648
  u16* piT  = (u16*)(ws + 50331648);          // 50331648 .. 56623104
  u16* poT  = (u16*)(ws + 56623104);          // 56623104 .. 58720256
  u16* xbf  = (u16*)(ws + 58720256);          // 58720256 .. 75497472 (dead after GEMM1)
  u16* vt   = (u16*)(ws + 75497472);          // 75497472 .. 92274688
  u16* obuf = (u16*)(ws + 58720256);          // reuses xbf slot

  convert_bf16<<<8192, 256, 0, stream>>>(x, xbf, 8388608 / 4);
  dim3 tb(32, 8);
  transpose_f32_bf16<<<dim3(96, 32), tb, 0, stream>>>(Pi, piT, 1024, 3072);
  transpose_f32_bf16<<<dim3(32, 32), tb, 0, stream>>>(Po, poT, 1024, 1024);

  gemm_v7<u16, 192, 1><<<dim3(16, 64), 256, 0, stream>>>(xbf, piT, qkv, vt,
                                                         8192, 3072, 1024);
  attn_fwd4<<<dim3(4, 16, 8), 512, 0, stream>>>(qkv, vt, obuf);
  gemm_v7<float, 128, 0><<<dim3(8, 64), 256, 0, stream>>>(obuf, poT, y, nullptr,
                                                          8192, 1024, 1024);
}

// Round 12
// 153.100 us; speedup vs baseline: 1.1430x; 1.0016x over previous
//
#include <hip/hip_runtime.h>

typedef unsigned short u16;
typedef __bf16 b16x8_t __attribute__((ext_vector_type(8)));
typedef unsigned short u16x8 __attribute__((ext_vector_type(8)));
typedef float f32x4 __attribute__((ext_vector_type(4)));

__device__ __forceinline__ u16 f2bf(float f) {
  union { float f; unsigned u; } x; x.f = f;
  unsigned r = x.u + 0x7fffu + ((x.u >> 16) & 1u);
  return (u16)(r >> 16);
}

__device__ __forceinline__ f32x4 mfma16(u16x8 a, u16x8 b, f32x4 c) {
  return __builtin_amdgcn_mfma_f32_16x16x32_bf16(
      __builtin_bit_cast(b16x8_t, a), __builtin_bit_cast(b16x8_t, b), c, 0, 0, 0);
}

__device__ __forceinline__ void gld_lds16(const void* g, void* l) {
  __builtin_amdgcn_global_load_lds(
      (const __attribute__((address_space(1))) void*)g,
      (__attribute__((address_space(3))) void*)l, 16, 0, 0);
}

__device__ __forceinline__ void store_out(float* p, float v) { *p = v; }
__device__ __forceinline__ void store_out(u16* p, float v) { *p = f2bf(v); }

// ---------------- elementwise f32 -> bf16 ----------------
__global__ void convert_bf16(const float* __restrict__ src, u16* __restrict__ dst, int n4) {
  int i = blockIdx.x * blockDim.x + threadIdx.x;
  if (i < n4) {
    float4 f = ((const float4*)src)[i];
    u16 a0 = f2bf(f.x), a1 = f2bf(f.y), a2 = f2bf(f.z), a3 = f2bf(f.w);
    unsigned lo = (unsigned)a0 | ((unsigned)a1 << 16);
    unsigned hi = (unsigned)a2 | ((unsigned)a3 << 16);
    ((uint2*)dst)[i] = make_uint2(lo, hi);
  }
}

// ---------------- f32 [R][C] -> bf16 transposed [C][R] ----------------
__global__ void transpose_f32_bf16(const float* __restrict__ src, u16* __restrict__ dst,
                                   int R, int Cn) {
  __shared__ float t[32][33];
  int c0 = blockIdx.x * 32, r0 = blockIdx.y * 32;
  int tx = threadIdx.x, ty = threadIdx.y;  // (32,8)
  for (int j = 0; j < 32; j += 8)
    t[ty + j][tx] = src[(size_t)(r0 + ty + j) * Cn + c0 + tx];
  __syncthreads();
  for (int j = 0; j < 32; j += 8)
    dst[(size_t)(c0 + ty + j) * R + r0 + tx] = f2bf(t[tx][ty + j]);
}

// ---------------- bf16 GEMM 8-phase (m201-style) for GEMM1 ----------------
// BM=256, BN=192, BK=64, 512 thr (8 waves 2Mx4N), per-wave 128x48 (acc[8][3]).
// Grid (16,32) = 512 blocks = EXACTLY 2.0 rounds @ 1 block/CU (112 KB LDS).
// Per K-tile 4 phases x 12 MFMA ({kk0,kk1}x{mq0,mq1}); B-frags reused across mq.
// Staging (region-exact, barrier-proven): iter {t0=2i(buf0), t1(buf1)} stages
// t1 @P1-P2, t2 @P4-P7, t3.B0 @P8. Counted vmcnt(1) at P4/P8 only (drains the
// next tile's 7 loads, keeps newest in flight; never 0 mid-loop).
// Swizzle: 16B-chunk ^= (row&7) via pre-swizzled source (R4-verified 0 confl).
// Epilogue: Q cols scaled 0.125; V cols written transposed to Vt (fused).
__global__ __launch_bounds__(512, 2) void gemm8p(const u16* __restrict__ A,
                                                 const u16* __restrict__ Bt,
                                                 u16* __restrict__ C,
                                                 u16* __restrict__ Vt,
                                                 int M, int N, int K) {
  __shared__ __align__(16) u16 sA[2][16384];  // [buf][256 rows x 64 k]
  __shared__ __align__(16) u16 sB[2][12288];  // [buf][192 rows x 64 k]
  const int tid = threadIdx.x, lane = tid & 63, wid = tid >> 6;
  const int hi = lane >> 4, ln = lane & 15;
  const int wr = wid >> 2, wc = wid & 3;

  // XCD-aware bijective swizzle (nwg = 512, %8 == 0)
  const int gdx = gridDim.x;
  const int nwg = gdx * gridDim.y;
  int wg = blockIdx.y * gdx + blockIdx.x;
  wg = (wg & 7) * (nwg >> 3) + (wg >> 3);
  const int m0 = (wg / gdx) * 256;
  const int n0 = (wg % gdx) * 192;

  // staging: quarter/third = 64 rows; thread -> row tid>>3, chunk tid&7 (16B);
  // source chunk pre-swizzled so linear LDS dest holds chunk^(row&7)
  const int srow = tid >> 3;
  const int sc = ((tid & 7) ^ (srow & 7)) * 8;
  const u16* gA = A + (size_t)(m0 + srow) * K + sc;
  const u16* gB = Bt + (size_t)(n0 + srow) * K + sc;
  const size_t K64 = (size_t)64 * K;

  auto stA = [&](int buf, int t, int q) {
    gld_lds16(gA + (size_t)q * K64 + t * 64, &sA[buf][q * 4096 + tid * 8]);
  };
  auto stB = [&](int buf, int t, int q) {
    gld_lds16(gB + (size_t)q * K64 + t * 64, &sB[buf][q * 4096 + tid * 8]);
  };

  // fragment read offsets (u16 units): elem = row*64 + ((kk*4+hi)^(row&7))*8,
  // row&7 == ln&7 for all fragment rows (row = 16*z + ln)
  int csw[2];
  csw[0] = ((hi) ^ (ln & 7)) * 8;
  csw[1] = ((4 + hi) ^ (ln & 7)) * 8;
  const int aRow = (wr * 128 + ln) * 64;                       // + (mq*64+i*16)*64 + csw
  const int bRow = (wc >> 1) * 6144 + ((wc & 1) * 48 + ln) * 64;  // + (j*16)*64 + csw

  f32x4 acc[8][3] = {};
  u16x8 af[4], bfk[3];

  auto LDA = [&](int buf, int mq, int kk) {
#pragma unroll
    for (int i = 0; i < 4; ++i)
      af[i] = *(const u16x8*)(&sA[buf][aRow + (mq * 64 + i * 16) * 64 + csw[kk]]);
  };
  auto LDB = [&](int buf, int kk) {
#pragma unroll
    for (int j = 0; j < 3; ++j)
      bfk[j] = *(const u16x8*)(&sB[buf][bRow + (j * 16) * 64 + csw[kk]]);
  };
  auto PRE = [&] {
    __builtin_amdgcn_s_barrier();
    asm volatile("s_waitcnt lgkmcnt(0)" ::: "memory");
    __builtin_amdgcn_sched_barrier(0);
    __builtin_amdgcn_s_setprio(1);
  };
  auto POST = [&] {
    __builtin_amdgcn_s_setprio(0);
    __builtin_amdgcn_sched_barrier(0);
    __builtin_amdgcn_s_barrier();
  };
  auto MMA12 = [&](int mq) {
#pragma unroll
    for (int i = 0; i < 4; ++i)
#pragma unroll
      for (int j = 0; j < 3; ++j)
        acc[mq * 4 + i][j] = mfma16(af[i], bfk[j], acc[mq * 4 + i][j]);
  };

  const int NT = K >> 6;  // 16
  // prologue: t0 fully (B0,B1,B2,A0..A3), t1.B0
  stB(0, 0, 0); stB(0, 0, 1); stB(0, 0, 2);
  stA(0, 0, 0); stA(0, 0, 1); stA(0, 0, 2); stA(0, 0, 3);
  stB(1, 1, 0);
  asm volatile("s_waitcnt vmcnt(1)" ::: "memory");
  __builtin_amdgcn_s_barrier();

  for (int it = 0; it < NT / 2; ++it) {
    const int t1 = 2 * it + 1, t2 = 2 * it + 2, t3 = 2 * it + 3;
    const bool s2 = t2 < NT, s3 = t3 < NT;
    // ---- tile t0 (buf0) ----
    // P1: kk0/mq0 + stage t1 {B1,B2,A0,A1} (buf1 idle; old tenant dead since prev P8)
    LDA(0, 0, 0); LDB(0, 0);
    stB(1, t1, 1); stB(1, t1, 2); stA(1, t1, 0); stA(1, t1, 1);
    PRE(); MMA12(0); POST();
    // P2: kk0/mq1 (bfk reused) + stage t1 {A2,A3}
    LDA(0, 1, 0);
    stA(1, t1, 2); stA(1, t1, 3);
    PRE(); MMA12(1); POST();
    // P3: kk1/mq0
    LDA(0, 0, 1); LDB(0, 1);
    PRE(); MMA12(0); POST();
    // P4: kk1/mq1 + stage t2.B0 (t0.B dead after P3 barrier)  [checkpoint]
    LDA(0, 1, 1);
    if (s2) stB(0, t2, 0);
    PRE(); MMA12(1);
    __builtin_amdgcn_s_setprio(0);
    __builtin_amdgcn_sched_barrier(0);
    if (s2) asm volatile("s_waitcnt vmcnt(1)" ::: "memory");  // t1's 7 landed
    else    asm volatile("s_waitcnt vmcnt(0)" ::: "memory");
    __builtin_amdgcn_s_barrier();
    // ---- tile t1 (buf1) ----
    // P5: kk0/mq0 + stage t2 {B1,B2}
    LDA(1, 0, 0); LDB(1, 0);
    if (s2) { stB(0, t2, 1); stB(0, t2, 2); }
    PRE(); MMA12(0); POST();
    // P6: kk0/mq1 + stage t2 {A0,A1} (t0.A dead after P4 barrier)
    LDA(1, 1, 0);
    if (s2) { stA(0, t2, 0); stA(0, t2, 1); }
    PRE(); MMA12(1); POST();
    // P7: kk1/mq0 + stage t2 {A2,A3}
    LDA(1, 0, 1); LDB(1, 1);
    if (s2) { stA(0, t2, 2); stA(0, t2, 3); }
    PRE(); MMA12(0); POST();
    // P8: kk1/mq1 + stage t3.B0 (t1.B dead after P7 barrier)  [checkpoint]
    LDA(1, 1, 1);
    if (s3) stB(1, t3, 0);
    PRE(); MMA12(1);
    __builtin_amdgcn_s_setprio(0);
    __builtin_amdgcn_sched_barrier(0);
    if (s3) asm volatile("s_waitcnt vmcnt(1)" ::: "memory");  // t2's 7 landed
    else    asm volatile("s_waitcnt vmcnt(0)" ::: "memory");
    __builtin_amdgcn_s_barrier();
  }

  // epilogue: C/D layout col = lane&15, row = (lane>>4)*4 + reg
#pragma unroll
  for (int i = 0; i < 8; ++i) {
    int rr = m0 + wr * 128 + i * 16 + hi * 4;
#pragma unroll
    for (int j = 0; j < 3; ++j) {
      int colw = wc * 48 + j * 16 + ln;      // 0..191
      if (colw >= 128) {
        // V: write directly transposed into Vt[(b*16+h)*64+kk][n]
        int h = n0 / 192, kk = colw - 128;
        int b = rr >> 10, n = rr & 1023;
        ushort4 pk;
        pk.x = f2bf(acc[i][j][0]); pk.y = f2bf(acc[i][j][1]);
        pk.z = f2bf(acc[i][j][2]); pk.w = f2bf(acc[i][j][3]);
        *(ushort4*)(Vt + ((size_t)(b * 16 + h) * 64 + kk) * 1024 + n) = pk;
      } else {
        float sc2 = (colw < 64) ? 0.125f : 1.f;
        int col = n0 + colw;
#pragma unroll
        for (int r = 0; r < 4; ++r)
          store_out(&C[(size_t)(rr + r) * N + col], acc[i][j][r] * sc2);
      }
    }
  }
}

// ---------------- bf16 GEMM v7 (GEMM2: BN=128, plain epilogue) ----------------
template <typename OutT, int BN, int EPI>
__global__ __launch_bounds__(256, 2) void gemm_v7(const u16* __restrict__ A,
                                                  const u16* __restrict__ Bt,
                                                  OutT* __restrict__ C,
                                                  u16* __restrict__ Vt,
                                                  int M, int N, int K) {
  constexpr int NB = BN / 64;
  constexpr int NJ = BN / 32;
  constexpr int NL = 2 + NB;
  __shared__ __align__(16) u16 sA[3][4096];
  __shared__ __align__(16) u16 sB[3][BN * 32];
  const int tid = threadIdx.x, lane = tid & 63, wid = tid >> 6;
  const int hi = lane >> 4, ln = lane & 15;
  const int wm = (wid >> 1) * 64, wn = (wid & 1) * (BN / 2);

  const int gdx = gridDim.x;
  const int nwg = gdx * gridDim.y;
  int wg = blockIdx.y * gdx + blockIdx.x;
  wg = (wg & 7) * (nwg >> 3) + (wg >> 3);
  const int m0 = (wg / gdx) * 128;
  const int n0 = (wg % gdx) * BN;

  const int sr = tid >> 2;
  const int scsw = ((tid & 3) ^ ((tid >> 3) & 3)) * 8;
  const u16* srcA = A + (size_t)(m0 + sr) * K + scsw;
  const u16* srcB = Bt + (size_t)(n0 + sr) * K + scsw;
  const size_t K64 = (size_t)64 * K;

  auto stage = [&](int buf, int t) {
    const int k0 = t * 32;
    gld_lds16(srcA + k0, &sA[buf][tid * 8]);
    gld_lds16(srcA + K64 + k0, &sA[buf][2048 + tid * 8]);
    gld_lds16(srcB + k0, &sB[buf][tid * 8]);
    gld_lds16(srcB + K64 + k0, &sB[buf][2048 + tid * 8]);
    if (NB > 2) gld_lds16(srcB + 2 * K64 + k0, &sB[buf][4096 + tid * 8]);
  };

  const int csw = (hi ^ ((ln >> 1) & 3)) * 8;
  int offA[4], offB[NJ];
#pragma unroll
  for (int i = 0; i < 4; ++i) offA[i] = (wm + i * 16 + ln) * 32 + csw;
#pragma unroll
  for (int j = 0; j < NJ; ++j) offB[j] = (wn + j * 16 + ln) * 32 + csw;

  f32x4 acc[4][NJ] = {};
  const int NT = K >> 5;

  stage(0, 0); stage(1, 1);
  if constexpr (NL == 5) asm volatile("s_waitcnt vmcnt(5)" ::: "memory");
  else                   asm volatile("s_waitcnt vmcnt(4)" ::: "memory");
  __builtin_amdgcn_s_barrier();

  int cb = 0, sb = 2;
  for (int kt = 0; kt < NT; ++kt) {
    u16x8 af[4], bf[NJ];
#pragma unroll
    for (int i = 0; i < 4; ++i) af[i] = *(const u16x8*)(&sA[cb][offA[i]]);
#pragma unroll
    for (int j = 0; j < NJ; ++j) bf[j] = *(const u16x8*)(&sB[cb][offB[j]]);
    if (kt + 2 < NT) {
      stage(sb, kt + 2);
      sb = (sb == 2) ? 0 : sb + 1;
      if constexpr (NL == 5) asm volatile("s_waitcnt vmcnt(5)" ::: "memory");
      else                   asm volatile("s_waitcnt vmcnt(4)" ::: "memory");
    } else {
      asm volatile("s_waitcnt vmcnt(0)" ::: "memory");
    }
    __builtin_amdgcn_s_barrier();
    asm volatile("s_waitcnt lgkmcnt(0)" ::: "memory");
    __builtin_amdgcn_sched_barrier(0);
    __builtin_amdgcn_s_setprio(1);
#pragma unroll
    for (int i = 0; i < 4; ++i)
#pragma unroll
      for (int j = 0; j < NJ; ++j)
        acc[i][j] = mfma16(af[i], bf[j], acc[i][j]);
    __builtin_amdgcn_s_setprio(0);
    __builtin_amdgcn_sched_barrier(0);
    __builtin_amdgcn_s_barrier();
    cb = (cb == 2) ? 0 : cb + 1;
  }

#pragma unroll
  for (int i = 0; i < 4; ++i) {
    int rr = m0 + wm + i * 16 + hi * 4;
#pragma unroll
    for (int j = 0; j < NJ; ++j) {
      int colw = wn + j * 16 + ln;
      if (EPI == 1 && colw >= 128) {
        int h = n0 / 192, kk = colw - 128;
        int b = rr >> 10, n = rr & 1023;
        ushort4 pk;
        pk.x = f2bf(acc[i][j][0]); pk.y = f2bf(acc[i][j][1]);
        pk.z = f2bf(acc[i][j][2]); pk.w = f2bf(acc[i][j][3]);
        *(ushort4*)(Vt + ((size_t)(b * 16 + h) * 64 + kk) * 1024 + n) = pk;
      } else {
        float sc = (EPI == 1 && colw < 64) ? 0.125f : 1.f;
        int col = n0 + colw;
#pragma unroll
        for (int r = 0; r < 4; ++r)
          store_out(&C[(size_t)(rr + r) * N + col], acc[i][j][r] * sc);
      }
    }
  }
}

// ---------------- causal flash attention v4 (unchanged from R11) ----------------
__global__ __launch_bounds__(512, 4) void attn_fwd4(const u16* __restrict__ QKV,
                                                    const u16* __restrict__ Vt,
                                                    u16* __restrict__ O) {
  __shared__ __align__(16) u16 sK[2][4096];
  __shared__ __align__(16) u16 sVt[2][4096];
  __shared__ __align__(16) u16 sP[8][16 * 72];
  const int tid = threadIdx.x, lane = tid & 63, wid = tid >> 6;
  const int z = blockIdx.x, h = blockIdx.y, bb = blockIdx.z;
  const size_t rowbase = (size_t)bb * 1024;
  const size_t vbase = ((size_t)bb * 16 + h) * 64;
  const int colQ = h * 192, colK = colQ + 64;
  const int hi = lane >> 4, ln = lane & 15;
  const int slr = lane >> 3;
  const int sle = ((lane & 7) ^ slr) * 8;
  u16* sPw = sP[wid];
  const u16x8 onesf = {0x3F80, 0x3F80, 0x3F80, 0x3F80, 0x3F80, 0x3F80, 0x3F80, 0x3F80};

  auto stageKV = [&](int buf, int nt) {
    const int n0g = nt * 64;
    gld_lds16(QKV + (rowbase + n0g + 8 * wid + slr) * 3072 + colK + sle,
              &sK[buf][wid * 512]);
    gld_lds16(Vt + (vbase + 8 * wid + slr) * 1024 + n0g + sle,
              &sVt[buf][wid * 512]);
  };

  for (int half = 0; half < 2; ++half) {
    const int mt = half ? (7 - z) : z;
    const int qrow0 = mt * 128 + wid * 16;
    const int ntiles = 2 * mt + 2;

    u16x8 qf[2];
#pragma unroll
    for (int kb = 0; kb < 2; ++kb)
      qf[kb] = *(const u16x8*)(QKV + (rowbase + qrow0 + ln) * 3072 + colQ + kb * 32 + hi * 8);

    f32x4 o[4] = {};
    f32x4 lacc = {0.f, 0.f, 0.f, 0.f};
    float mrow[4];
#pragma unroll
    for (int r = 0; r < 4; ++r) mrow[r] = -1e30f;

    stageKV(0, 0);
    for (int nt = 0; nt < ntiles; ++nt) {
      __syncthreads();
      if (nt + 1 < ntiles) stageKV((nt + 1) & 1, nt + 1);
      const int buf = nt & 1;
      const int n0g = nt * 64;
      if (n0g <= qrow0 + 15) {
        f32x4 s[4] = {};
        __builtin_amdgcn_s_setprio(1);
#pragma unroll
        for (int kb = 0; kb < 2; ++kb)
#pragma unroll
          for (int j = 0; j < 4; ++j) {
            int row = j * 16 + ln;
            int cb = (kb * 64 + hi * 16) ^ ((row & 7) << 4);
            u16x8 kfr = *(const u16x8*)(&sK[buf][(row * 128 + cb) >> 1]);
            s[j] = mfma16(qf[kb], kfr, s[j]);
          }
        __builtin_amdgcn_s_setprio(0);
        if (n0g + 63 > qrow0) {
#pragma unroll
          for (int j = 0; j < 4; ++j) {
            int col = n0g + j * 16 + ln;
#pragma unroll
            for (int r = 0; r < 4; ++r)
              if (col > qrow0 + hi * 4 + r) s[j][r] = -3e38f;
          }
        }
        float tmv[4];
#pragma unroll
        for (int r = 0; r < 4; ++r) {
          float tm = fmaxf(fmaxf(s[0][r], s[1][r]), fmaxf(s[2][r], s[3][r]));
#pragma unroll
          for (int d = 1; d < 16; d <<= 1) tm = fmaxf(tm, __shfl_xor(tm, d, 64));
          tmv[r] = tm;
        }
        bool need = (tmv[0] > mrow[0] + 8.f) | (tmv[1] > mrow[1] + 8.f) |
                    (tmv[2] > mrow[2] + 8.f) | (tmv[3] > mrow[3] + 8.f);
        if (__any(need)) {
#pragma unroll
          for (int r = 0; r < 4; ++r) {
            float mnew = fmaxf(mrow[r], tmv[r]);
            float corr = __expf(mrow[r] - mnew);
            mrow[r] = mnew;
            lacc[r] *= corr;
#pragma unroll
            for (int dt = 0; dt < 4; ++dt) o[dt][r] *= corr;
          }
        }
#pragma unroll
        for (int j = 0; j < 4; ++j)
#pragma unroll
          for (int r = 0; r < 4; ++r)
            sPw[(hi * 4 + r) * 72 + j * 16 + ln] = f2bf(__expf(s[j][r] - mrow[r]));
        u16x8 pf[2];
#pragma unroll
        for (int kb2 = 0; kb2 < 2; ++kb2)
          pf[kb2] = *(const u16x8*)(&sPw[ln * 72 + kb2 * 32 + hi * 8]);
        __builtin_amdgcn_s_setprio(1);
        lacc = mfma16(pf[0], onesf, lacc);
        lacc = mfma16(pf[1], onesf, lacc);
#pragma unroll
        for (int dt = 0; dt < 4; ++dt)
#pragma unroll
          for (int kb2 = 0; kb2 < 2; ++kb2) {
            int row = dt * 16 + ln;
            int cb = (kb2 * 64 + hi * 16) ^ ((row & 7) << 4);
            u16x8 vfr = *(const u16x8*)(&sVt[buf][(row * 128 + cb) >> 1]);
            o[dt] = mfma16(pf[kb2], vfr, o[dt]);
          }
        __builtin_amdgcn_s_setprio(0);
      }
    }
#pragma unroll
    for (int r = 0; r < 4; ++r) {
      float inv = 1.f / lacc[r];
#pragma unroll
      for (int dt = 0; dt < 4; ++dt)
        O[(rowbase + qrow0 + hi * 4 + r) * 1024 + h * 64 + dt * 16 + ln] =
            f2bf(o[dt][r] * inv);
    }
  }
}

extern "C" void kernel_launch(void* const* d_in, const int* in_sizes, int n_in,
                              void* d_out, int out_size, void* d_ws, size_t ws_size,
                              hipStream_t stream) {
  const float* x = (const float*)d_in[0];
  const float* Pi = (const float*)d_in[1];
  const float* Po = (const float*)d_in[2];
  float* y = (float*)d_out;
  char* ws = (char*)d_ws;

  u16* qkv  = (u16*)(ws);                     // 0        .. 50331648
  u16* piT  = (u16*)(ws + 50331648);          // 50331648 .. 56623104
  u16* poT  = (u16*)(ws + 56623104);          // 56623104 .. 58720256
  u16* xbf  = (u16*)(ws + 58720256);          // 58720256 .. 75497472 (dead after GEMM1)
  u16* vt   = (u16*)(ws + 75497472);          // 75497472 .. 92274688
  u16* obuf = (u16*)(ws + 58720256);          // reuses xbf slot

  convert_bf16<<<8192, 256, 0, stream>>>(x, xbf, 8388608 / 4);
  dim3 tb(32, 8);
  transpose_f32_bf16<<<dim3(96, 32), tb, 0, stream>>>(Pi, piT, 1024, 3072);
  transpose_f32_bf16<<<dim3(32, 32), tb, 0, stream>>>(Po, poT, 1024, 1024);

  gemm8p<<<dim3(16, 32), 512, 0, stream>>>(xbf, piT, qkv, vt, 8192, 3072, 1024);
  attn_fwd4<<<dim3(4, 16, 8), 512, 0, stream>>>(qkv, vt, obuf);
  gemm_v7<float, 128, 0><<<dim3(8, 64), 256, 0, stream>>>(obuf, poT, y, nullptr,
                                                          8192, 1024, 1024);
}